// Round 1
// baseline (636.879 us; speedup 1.0000x reference)
//
#include <hip/hip_runtime.h>
#include <math.h>

// Problem constants (from reference): x is [D=32, N=96*96=9216] fp32.
// 3 iterations of: w(i,j)=exp(3*<x_i,x_j>); x[:,j] <- 0.5*sum_i w*x[:,i]/sum_i w + 0.5*x[:,j]
// Output layout: [x3 (final)][x1][x2][x3]  (final, then stack(outs))

#define D 32
#define NPIX 9216
#define NJ_TILE 256          // j columns per block == blockDim.x
#define NI_CHUNKS 16         // i-split factor (for grid saturation)
#define I_PER_BLOCK (NPIX / NI_CHUNKS)   // 576
#define I_SUB 64             // LDS staging sub-chunk
#define XS_STRIDE 36         // 32 + 4 pad floats; 36 = 9 float4 -> rows stay 16B-aligned

// Accumulate num[d][j] += sum_i w(i,j)*x[d][i] and den[j] += sum_i w(i,j)
// over this block's i-range, via fp32 atomics into workspace.
__global__ __launch_bounds__(256) void accum_kernel(const float* __restrict__ xin,
                                                    float* __restrict__ num,
                                                    float* __restrict__ den)
{
    __shared__ float xs[I_SUB * XS_STRIDE];   // xs[ii][d], padded stride

    const int jt = blockIdx.x % (NPIX / NJ_TILE);   // 36 j-tiles
    const int ic = blockIdx.x / (NPIX / NJ_TILE);   // 16 i-chunks
    const int j  = jt * NJ_TILE + threadIdx.x;
    const int i0 = ic * I_PER_BLOCK;

    // Per-thread query column q[d] = x[d][j]  (coalesced across threads)
    float q[D];
    #pragma unroll
    for (int d = 0; d < D; ++d) q[d] = xin[d * NPIX + j];

    float acc_num[D];
    #pragma unroll
    for (int d = 0; d < D; ++d) acc_num[d] = 0.f;
    float acc_den = 0.f;

    const int ii_w = threadIdx.x & (I_SUB - 1);   // 0..63
    const int d0   = threadIdx.x >> 6;            // 0..3

    for (int is = 0; is < I_PER_BLOCK; is += I_SUB) {
        __syncthreads();
        // Stage xs[ii][d] = x[d][i0+is+ii]; global reads coalesced over ii.
        #pragma unroll
        for (int r = 0; r < 8; ++r) {
            int d = d0 + 4 * r;
            xs[ii_w * XS_STRIDE + d] = xin[d * NPIX + i0 + is + ii_w];
        }
        __syncthreads();

        for (int ii2 = 0; ii2 < I_SUB; ++ii2) {
            // Broadcast-read key/value column i into registers (float4 x8)
            const float4* xrow = (const float4*)(&xs[ii2 * XS_STRIDE]);
            float4 xv[8];
            #pragma unroll
            for (int r = 0; r < 8; ++r) xv[r] = xrow[r];

            float dot = 0.f;
            #pragma unroll
            for (int r = 0; r < 8; ++r) {
                dot += xv[r].x * q[4*r+0];
                dot += xv[r].y * q[4*r+1];
                dot += xv[r].z * q[4*r+2];
                dot += xv[r].w * q[4*r+3];
            }
            float w = __expf(3.0f * dot);
            acc_den += w;
            #pragma unroll
            for (int r = 0; r < 8; ++r) {
                acc_num[4*r+0] += w * xv[r].x;
                acc_num[4*r+1] += w * xv[r].y;
                acc_num[4*r+2] += w * xv[r].z;
                acc_num[4*r+3] += w * xv[r].w;
            }
        }
    }

    // Commit partials (coalesced per d; 16 blocks contend per address -> light)
    #pragma unroll
    for (int d = 0; d < D; ++d) atomicAdd(&num[d * NPIX + j], acc_num[d]);
    atomicAdd(&den[j], acc_den);
}

// out[d][j] = 0.5*num[d][j]/den[j] + 0.5*xin[d][j]; optional second write (final slot)
__global__ __launch_bounds__(256) void combine_kernel(const float* __restrict__ xin,
                                                      const float* __restrict__ num,
                                                      const float* __restrict__ den,
                                                      float* __restrict__ xout,
                                                      float* __restrict__ xfinal)
{
    int idx = blockIdx.x * blockDim.x + threadIdx.x;   // 0 .. D*NPIX-1
    int j = idx % NPIX;
    float v = 0.5f * num[idx] / den[j] + 0.5f * xin[idx];
    xout[idx] = v;
    if (xfinal) xfinal[idx] = v;
}

extern "C" void kernel_launch(void* const* d_in, const int* in_sizes, int n_in,
                              void* d_out, int out_size, void* d_ws, size_t ws_size,
                              hipStream_t stream)
{
    const float* x0 = (const float*)d_in[0];
    float* out = (float*)d_out;            // [x3][x1][x2][x3], each D*NPIX floats
    float* num = (float*)d_ws;             // D*NPIX floats
    float* den = num + (size_t)D * NPIX;   // NPIX floats

    const size_t slot = (size_t)D * NPIX;  // 294912

    for (int t = 0; t < 3; ++t) {
        // zero accumulators (ws is re-poisoned 0xAA before every timed call)
        hipMemsetAsync(d_ws, 0, (slot + NPIX) * sizeof(float), stream);

        const float* xin = (t == 0) ? x0 : (out + (size_t)t * slot);
        float* xout = out + (size_t)(t + 1) * slot;
        float* xfinal = (t == 2) ? out : nullptr;

        accum_kernel<<<dim3(NI_CHUNKS * (NPIX / NJ_TILE)), dim3(NJ_TILE), 0, stream>>>(
            xin, num, den);
        combine_kernel<<<dim3((D * NPIX) / 256), dim3(256), 0, stream>>>(
            xin, num, den, xout, xfinal);
    }
}

// Round 2
// 178.594 us; speedup vs baseline: 3.5661x; 3.5661x over previous
//
#include <hip/hip_runtime.h>
#include <hip/hip_bf16.h>
#include <math.h>

// x: [D=32, N=9216] fp32. 3 iters: w(i,j)=exp(3*<x_i,x_j>),
// x[:,j] <- 0.5*sum_i w*x[:,i]/sum_i w + 0.5*x[:,j]
// Output: [x3][x1][x2][x3].
// Strategy: bf16 MFMA flash-style. S-tile = xT*x via mfma_16x16x32 (K=d=32),
// w=exp2(C3*S) in C-layout regs, LDS round-trip to B-layout, PV mfma (K=i=32).

#define D 32
#define NPIX 9216
#define NSPLIT 16            // i-split for grid saturation (atomic combine)
#define JB 128               // j per block = 4 waves * 32 j
#define NJB (NPIX / JB)      // 72 j-blocks
#define IPB (NPIX / NSPLIT)  // 576 i per block
#define XST 56               // LDS row stride (shorts) for staged x tiles (16B-aligned rows, bank-spread)
#define WST 56               // LDS row stride for w tiles
#define TS  40               // combine transpose tile stride (shorts)

typedef __attribute__((ext_vector_type(8))) short short8;
typedef __attribute__((ext_vector_type(4))) float f32x4;
typedef __attribute__((ext_vector_type(2))) unsigned int u32x2;

#if __has_builtin(__builtin_amdgcn_exp2f)
#define EXP2F __builtin_amdgcn_exp2f
#else
#define EXP2F exp2f
#endif

#define C3 4.32808512266689f   // 3 * log2(e)

__device__ __forceinline__ unsigned pack2_bf16(float a, float b) {
    union { __hip_bfloat162 h2; unsigned u; } c;
    c.h2 = __float22bfloat162_rn(make_float2(a, b));
    return c.u;
}
__device__ __forceinline__ short pack1_bf16(float a) {
    union { __hip_bfloat16 h; unsigned short s; } c;
    c.h = __float2bfloat16(a);
    return (short)c.s;
}

// num[d][j] += sum_i w(i,j)*x[d][i]; den[j] += sum_i w(i,j), over block's i-range.
__global__ __launch_bounds__(256) void accum_kernel(
    const short* __restrict__ xb,    // bf16 bits [D][NPIX]
    const short* __restrict__ xbT,   // bf16 bits [NPIX][D]
    float* __restrict__ num, float* __restrict__ den)
{
    __shared__ __align__(16) short xiT_s[32 * XST];        // [ii][d]
    __shared__ __align__(16) short xi_s [32 * XST];        // [d][ii]
    __shared__ __align__(16) short w_s[4][2][16 * WST];    // per wave, per j-tile: [j_local][ii]

    const int t = threadIdx.x;
    const int wid = t >> 6, lane = t & 63, quad = lane >> 4, m = lane & 15;
    const int bj = blockIdx.x % NJB, bi = blockIdx.x / NJB;
    const int j0 = bj * JB + wid * 32;
    const int i0b = bi * IPB;

    // Hoisted QK B-frags (j side): B[k=d][n=j_local], lane: n=m, k=quad*8+e
    short8 bfrag[2];
#pragma unroll
    for (int jt = 0; jt < 2; ++jt)
        bfrag[jt] = *(const short8*)&xbT[(j0 + jt * 16 + m) * D + quad * 8];

    f32x4 acc[2][2] = {};            // [d-tile][j-tile], C-layout
    float dacc[2] = {0.f, 0.f};

    const int s_r = t >> 3, s_c = (t & 7) * 4;   // staging coords (row, col*4)

    for (int ic = 0; ic < IPB; ic += 32) {
        const int i0 = i0b + ic;
        __syncthreads();
        // cooperative stage: 2 KB per layout, coalesced global, 8B LDS writes
        *(u32x2*)&xiT_s[s_r * XST + s_c] = *(const u32x2*)&xbT[(i0 + s_r) * D + s_c];
        *(u32x2*)&xi_s [s_r * XST + s_c] = *(const u32x2*)&xb [s_r * NPIX + i0 + s_c];
        __syncthreads();

        // A-frags: lane m = row, k = quad*8+e contiguous 16B
        short8 aT[2], aV[2];
#pragma unroll
        for (int it = 0; it < 2; ++it)
            aT[it] = *(const short8*)&xiT_s[(it * 16 + m) * XST + quad * 8];
#pragma unroll
        for (int dt = 0; dt < 2; ++dt)
            aV[dt] = *(const short8*)&xi_s[(dt * 16 + m) * XST + quad * 8];

#pragma unroll
        for (int jt = 0; jt < 2; ++jt) {
            f32x4 z = {0.f, 0.f, 0.f, 0.f};
            // S[i_local][j_local] for i-tiles 0,1  (M=i, N=j, K=d=32)
            f32x4 s0 = __builtin_amdgcn_mfma_f32_16x16x32_bf16(aT[0], bfrag[jt], z, 0, 0, 0);
            f32x4 s1 = __builtin_amdgcn_mfma_f32_16x16x32_bf16(aT[1], bfrag[jt], z, 0, 0, 0);

            float w[8];
#pragma unroll
            for (int r = 0; r < 4; ++r) { w[r]     = EXP2F(C3 * s0[r]);
                                          w[4 + r] = EXP2F(C3 * s1[r]); }
#pragma unroll
            for (int r = 0; r < 8; ++r) dacc[jt] += w[r];

            // C-layout -> [j][i] LDS: lane holds w[i=it*16+quad*4+r][j=m]
            u32x2 p0, p1;
            p0.x = pack2_bf16(w[0], w[1]); p0.y = pack2_bf16(w[2], w[3]);
            p1.x = pack2_bf16(w[4], w[5]); p1.y = pack2_bf16(w[6], w[7]);
            *(u32x2*)&w_s[wid][jt][m * WST +      quad * 4] = p0;
            *(u32x2*)&w_s[wid][jt][m * WST + 16 + quad * 4] = p1;

            // B-frag of w: B[k=ii][n=j_local]: lane n=m, k=quad*8+e contiguous
            short8 wb = *(const short8*)&w_s[wid][jt][m * WST + quad * 8];

            // num[d][j] += x[d][i] * w[i][j]  (M=d, N=j, K=ii=32)
            acc[0][jt] = __builtin_amdgcn_mfma_f32_16x16x32_bf16(aV[0], wb, acc[0][jt], 0, 0, 0);
            acc[1][jt] = __builtin_amdgcn_mfma_f32_16x16x32_bf16(aV[1], wb, acc[1][jt], 0, 0, 0);
        }
    }

    // commit num partials: C-layout row=quad*4+r (d), col=m (j)
#pragma unroll
    for (int dt = 0; dt < 2; ++dt)
#pragma unroll
        for (int jt = 0; jt < 2; ++jt)
#pragma unroll
            for (int r = 0; r < 4; ++r)
                atomicAdd(&num[(dt * 16 + quad * 4 + r) * NPIX + j0 + jt * 16 + m],
                          acc[dt][jt][r]);
    // den: reduce over quads (lanes m, m+16, m+32, m+48)
#pragma unroll
    for (int jt = 0; jt < 2; ++jt) {
        float v = dacc[jt];
        v += __shfl_xor(v, 16, 64);
        v += __shfl_xor(v, 32, 64);
        if (quad == 0) atomicAdd(&den[j0 + jt * 16 + m], v);
    }
}

// v = 0.5*num/den + 0.5*xin (or v = xin if !do_ms). Writes xout/xfinal (fp32),
// xb (bf16 [D][N]) and xbT (bf16 [N][D] via LDS transpose). Re-zeros num/den
// for the next accum. Block: 64 i x 32 d; thread t: i=i0+(t&63), d=(t>>6)*8..+7.
__global__ __launch_bounds__(256) void combine_kernel(
    const float* __restrict__ xin, float* __restrict__ num,
    float* __restrict__ den, float* __restrict__ xout,
    float* __restrict__ xfinal, short* __restrict__ xb, short* __restrict__ xbT,
    int do_ms)
{
    __shared__ __align__(16) short tile[64 * TS];   // [i_local][d]
    const int t = threadIdx.x;
    const int il = t & 63, q = t >> 6;
    const int i = blockIdx.x * 64 + il;
    const int d0 = q * 8;

    float inv = 0.f;
    if (do_ms) inv = 0.5f / den[i];

#pragma unroll
    for (int dd = 0; dd < 8; ++dd) {
        const int d = d0 + dd;
        const int idx = d * NPIX + i;
        float v;
        if (do_ms) {
            v = num[idx] * inv + 0.5f * xin[idx];
            xout[idx] = v;
            if (xfinal) xfinal[idx] = v;
        } else {
            v = xin[idx];
        }
        num[idx] = 0.f;                 // pre-zero for next accum
        short b = pack1_bf16(v);
        xb[idx] = b;
        tile[il * TS + d] = b;
    }
    __syncthreads();
    if (q == 0) den[i] = 0.f;           // after all den reads
    // transposed rows: thread t writes xbT[i][q*8..q*8+7] (16B)
    *(short8*)&xbT[i * D + d0] = *(const short8*)&tile[il * TS + d0];
}

extern "C" void kernel_launch(void* const* d_in, const int* in_sizes, int n_in,
                              void* d_out, int out_size, void* d_ws, size_t ws_size,
                              hipStream_t stream)
{
    const float* x0 = (const float*)d_in[0];
    float* out = (float*)d_out;              // [x3][x1][x2][x3]
    const size_t slot = (size_t)D * NPIX;

    float* num = (float*)d_ws;               // D*NPIX f32
    float* den = num + slot;                 // NPIX f32
    short* xb  = (short*)(den + NPIX);       // D*NPIX bf16
    short* xbT = xb + slot;                  // NPIX*D bf16
    // ws usage: ~2.3 MB

    // convert x0 -> xb/xbT, zero num/den
    combine_kernel<<<dim3(NPIX / 64), dim3(256), 0, stream>>>(
        x0, num, den, nullptr, nullptr, xb, xbT, 0);

    for (int t = 0; t < 3; ++t) {
        accum_kernel<<<dim3(NJB * NSPLIT), dim3(256), 0, stream>>>(xb, xbT, num, den);
        const float* xin = (t == 0) ? x0 : (out + (size_t)t * slot);
        combine_kernel<<<dim3(NPIX / 64), dim3(256), 0, stream>>>(
            xin, num, den, out + (size_t)(t + 1) * slot,
            (t == 2) ? out : nullptr, xb, xbT, 1);
    }
}